// Round 2
// baseline (1019.369 us; speedup 1.0000x reference)
//
#include <hip/hip_runtime.h>

typedef unsigned short u16;
typedef __bf16 bf16x8 __attribute__((ext_vector_type(8)));
typedef __bf16 bf16x2 __attribute__((ext_vector_type(2)));
typedef float f32x4 __attribute__((ext_vector_type(4)));

#define MFMA(a,b,c) __builtin_amdgcn_mfma_f32_16x16x32_bf16(a,b,c,0,0,0)

static __device__ __forceinline__ u16 f2bf(float f){
  unsigned u = __float_as_uint(f);
  u = u + 0x7FFFu + ((u>>16)&1u);   // RNE
  return (u16)(u>>16);
}

static __device__ __forceinline__ unsigned pk2(float a, float b){
#if __has_builtin(__builtin_amdgcn_cvt_pk_bf16_f32)
  bf16x2 v = __builtin_amdgcn_cvt_pk_bf16_f32(a,b);
  return __builtin_bit_cast(unsigned, v);
#else
  return (unsigned)f2bf(a) | ((unsigned)f2bf(b)<<16);
#endif
}

static __device__ __forceinline__ float bfbits2f(unsigned b){
  return __uint_as_float(b<<16);
}

static __device__ __forceinline__ f32x4 fzero(){
  f32x4 z; z[0]=0.f; z[1]=0.f; z[2]=0.f; z[3]=0.f; return z;
}

// ws layout (u16): [0,196608) qkv_w bf16 (Q rows pre-scaled), [196608,262144) proj_w bf16,
//                  [262144,294912) bias transposed [h][k][q] bf16
__global__ void cvt_w(const float* __restrict__ qw, const float* __restrict__ pw,
                      const float* __restrict__ bias, u16* __restrict__ o){
  int i = blockIdx.x*512 + threadIdx.x;   // 576 blocks covers 294912 exactly
  float v;
  if (i < 196608) { v = qw[i]; if (i < 65536) v *= 0.17677669529663687f; }  // fold 1/sqrt(32) into Wq
  else if (i < 262144) v = pw[i-196608];
  else { int bi = i-262144; int h = bi>>12, k = (bi>>6)&63, q = bi&63;
         v = bias[(h<<12)+(q<<6)+k]; }
  o[i] = f2bf(v);
}

// ---- fused window attention: 1 window / 512-thread block (8 waves), 2 blocks/CU ----
__global__ __launch_bounds__(512,4) void swin(
    const float* __restrict__ x, const u16* __restrict__ wqkv,
    const u16* __restrict__ wproj, const float* __restrict__ pb,
    const u16* __restrict__ biasT, float* __restrict__ out){

  // All tiles flat, XOR-swizzled on 16B chunks -> no padding, no conflicts.
  __shared__ u16 Xs[64*256];    // 32 KB: x window bf16; later aliased as Os
  __shared__ u16 QKs[8192];     // 16 KB: [hl][Q 2048 | K 2048]; P[64][64] overlays per head
  __shared__ u16 Vts[4096];     //  8 KB: [hl][d][tok]

  const int tid = threadIdx.x;
  const int wv = tid>>6, lane = tid&63, l15 = lane&15, quad = lane>>4;
  const int w = blockIdx.x, bb = w>>10, wh = (w>>5)&31, ww = w&31;
  const size_t obase = ((size_t)bb)<<24;

  // ---- stage x -> bf16 LDS (swizzle: chunk ^= t&7) ----
  {
    const float* xb = x + obase;
    #pragma unroll
    for (int i = 0; i < 8; ++i) {
      int t = i*8 + wv;                 // wave-uniform token
      int c4 = lane;                    // float4 index within token
      int pix = (wh*8 + (t>>3))*256 + ww*8 + (t&7);
      const float4 v = *(const float4*)(xb + (size_t)pix*256 + c4*4);
      unsigned lo = pk2(v.x, v.y), hi = pk2(v.z, v.w);
      int addr = t*256 + ((((c4>>1)^(t&7))<<3)) + (c4&1)*4;
      *(uint2*)&Xs[addr] = make_uint2(lo,hi);
    }
  }
  __syncthreads();

  // QKV split: wave -> (token-pair th, d-group dg of 3 d-tiles among 12)
  const int th = wv&1, dg = wv>>1;
  int base0[3], hlj[3], tyj[3], dtj[3], isv[3];
  #pragma unroll
  for (int jl = 0; jl < 3; ++jl) {
    int j = dg*3 + jl, hl = j/6, r = j%6, ty = r>>1, dt = r&1;
    hlj[jl]=hl; tyj[jl]=ty; dtj[jl]=dt; isv[jl]=(ty==2);
    base0[jl] = ty*256 + hl*32 + dt*16;
  }
  // attention split: wave -> (head hl_a, q-tile qt)
  const int hl_a = wv>>2, qt = wv&3;
  const int q = qt*16 + l15;            // this lane's q-row (S^T col)
  const int x7 = l15&7;

  unsigned opkA[4][2], opkB[4][2];      // packed O^T fragments per slot, per d-tile

  #pragma unroll
  for (int s = 0; s < 4; ++s) {
    // ---------- QKV GEMM, heads 2s / 2s+1 ----------
    {
      f32x4 acc[3][2];
      #pragma unroll
      for (int a = 0; a < 3; ++a){ acc[a][0]=fzero(); acc[a][1]=fzero(); }
      const u16* wp0 = wqkv + (size_t)(base0[0] + s*64 + l15)*256 + quad*8;
      const u16* wp1 = wqkv + (size_t)(base0[1] + s*64 + l15)*256 + quad*8;
      const u16* wp2 = wqkv + (size_t)(base0[2] + s*64 + l15)*256 + quad*8;
      const int tr0 = (2*th)*16 + l15, tr1 = tr0 + 16;
      #pragma unroll
      for (int kk = 0; kk < 8; ++kk) {
        int off = (((kk*4+quad)^x7)<<3);
        bf16x8 xf0 = *(const bf16x8*)&Xs[tr0*256 + off];
        bf16x8 xf1 = *(const bf16x8*)&Xs[tr1*256 + off];
        bf16x8 wf0 = *(const bf16x8*)wp0; wp0 += 32;
        bf16x8 wf1 = *(const bf16x8*)wp1; wp1 += 32;
        bf16x8 wf2 = *(const bf16x8*)wp2; wp2 += 32;
        if (isv[0]) { acc[0][0]=MFMA(xf0,wf0,acc[0][0]); acc[0][1]=MFMA(xf1,wf0,acc[0][1]); }
        else        { acc[0][0]=MFMA(wf0,xf0,acc[0][0]); acc[0][1]=MFMA(wf0,xf1,acc[0][1]); }
        if (isv[1]) { acc[1][0]=MFMA(xf0,wf1,acc[1][0]); acc[1][1]=MFMA(xf1,wf1,acc[1][1]); }
        else        { acc[1][0]=MFMA(wf1,xf0,acc[1][0]); acc[1][1]=MFMA(wf1,xf1,acc[1][1]); }
        if (isv[2]) { acc[2][0]=MFMA(xf0,wf2,acc[2][0]); acc[2][1]=MFMA(xf1,wf2,acc[2][1]); }
        else        { acc[2][0]=MFMA(wf2,xf0,acc[2][0]); acc[2][1]=MFMA(wf2,xf1,acc[2][1]); }
      }
      // packed epilogue
      #pragma unroll
      for (int jl = 0; jl < 3; ++jl)
        #pragma unroll
        for (int tl = 0; tl < 2; ++tl) {
          f32x4 a = acc[jl][tl];
          unsigned lo = pk2(a[0],a[1]), hi = pk2(a[2],a[3]);
          if (!isv[jl]) {     // Q/K swapped: col=tok, regs = 4 consecutive d
            int t = (2*th+tl)*16 + l15;
            int d0 = dtj[jl]*16 + quad*4;
            int addr = hlj[jl]*4096 + tyj[jl]*2048 + t*32 + (((d0>>3)^(t&3))<<3) + (d0&7);
            *(uint2*)&QKs[addr] = make_uint2(lo,hi);
          } else {            // V normal: col=d, regs = 4 consecutive tok
            int d = dtj[jl]*16 + l15;
            int t0 = (2*th+tl)*16 + quad*4;
            int addr = hlj[jl]*2048 + d*64 + (((t0>>3)^(d&7))<<3) + (t0&7);
            *(uint2*)&Vts[addr] = make_uint2(lo,hi);
          }
        }
    }
    __syncthreads();   // #1: Q/K/Vt visible; Xs reads done

    // ---------- S^T = K Q^T (+bias), softmax over k (in-lane + 2 shuffles) ----------
    u16* Ph = &QKs[hl_a*4096];
    const u16* Kh = Ph + 2048;
    float sv[4][4]; float rinv;
    {
      bf16x8 qf = *(const bf16x8*)&Ph[q*32 + ((quad^(q&3))<<3)];   // Q region (pre-overlay)
      f32x4 sacc[4];
      #pragma unroll
      for (int mt = 0; mt < 4; ++mt) {
        int kt = mt*16 + l15;
        bf16x8 kf = *(const bf16x8*)&Kh[kt*32 + ((quad^(kt&3))<<3)];
        sacc[mt] = MFMA(kf, qf, fzero());
      }
      const u16* bT = biasT + (2*s + hl_a)*4096 + qt*16 + l15;
      float mx = -3.4e38f;
      #pragma unroll
      for (int mt = 0; mt < 4; ++mt)
        #pragma unroll
        for (int e = 0; e < 4; ++e) {
          float v = sacc[mt][e] + bfbits2f(bT[(mt*16 + quad*4 + e)*64]);
          sv[mt][e] = v; mx = fmaxf(mx, v);
        }
      mx = fmaxf(mx, __shfl_xor(mx, 16, 64));
      mx = fmaxf(mx, __shfl_xor(mx, 32, 64));
      float sum = 0.f;
      #pragma unroll
      for (int mt = 0; mt < 4; ++mt)
        #pragma unroll
        for (int e = 0; e < 4; ++e) { float p = __expf(sv[mt][e]-mx); sv[mt][e]=p; sum+=p; }
      sum += __shfl_xor(sum, 16, 64);
      sum += __shfl_xor(sum, 32, 64);
      rinv = 1.0f / sum;
    }
    __syncthreads();   // #2: all Q/K reads done; safe to overlay P

    // ---------- P write (packed), then O^T = V^T P^T (reads own P rows) ----------
    #pragma unroll
    for (int mt = 0; mt < 4; ++mt) {
      int k0 = mt*16 + quad*4;
      unsigned lo = pk2(sv[mt][0],sv[mt][1]), hi = pk2(sv[mt][2],sv[mt][3]);
      int addr = q*64 + (((k0>>3)^(q&7))<<3) + (k0&7);
      *(uint2*)&Ph[addr] = make_uint2(lo,hi);
    }
    {
      const u16* Vh = &Vts[hl_a*2048];
      f32x4 oacc[2]; oacc[0]=fzero(); oacc[1]=fzero();
      #pragma unroll
      for (int kk = 0; kk < 2; ++kk) {
        bf16x8 pf = *(const bf16x8*)&Ph[q*64 + (((kk*4+quad)^(q&7))<<3)];
        #pragma unroll
        for (int dt = 0; dt < 2; ++dt) {
          int d = dt*16 + l15;
          bf16x8 vf = *(const bf16x8*)&Vh[d*64 + (((kk*4+quad)^(d&7))<<3)];
          oacc[dt] = MFMA(vf, pf, oacc[dt]);
        }
      }
      #pragma unroll
      for (int dt = 0; dt < 2; ++dt) {
        opkA[s][dt] = pk2(oacc[dt][0]*rinv, oacc[dt][1]*rinv);
        opkB[s][dt] = pk2(oacc[dt][2]*rinv, oacc[dt][3]*rinv);
      }
    }
    if (s == 3) {
      // Os overlays Xs (dead since slot-3 barrier #1). tok = q for every slot.
      #pragma unroll
      for (int s2 = 0; s2 < 4; ++s2)
        #pragma unroll
        for (int dt = 0; dt < 2; ++dt) {
          int ch = (2*s2 + hl_a)*32 + dt*16 + quad*4;
          int addr = q*256 + (((ch>>3)^(q&7))<<3) + (ch&7);
          *(uint2*)&Xs[addr] = make_uint2(opkA[s2][dt], opkB[s2][dt]);
        }
    }
    __syncthreads();   // #3: P/Vt reads done (next slot may overwrite); s==3: Os visible
  }

  // ---------- proj GEMM + bias, fp32 stores ----------
  {
    f32x4 pacc[4][2];
    #pragma unroll
    for (int m = 0; m < 4; ++m){ pacc[m][0]=fzero(); pacc[m][1]=fzero(); }
    const u16* wpA = wproj + (size_t)(wv*32 + l15)*256 + quad*8;
    const u16* wpB = wpA + 16*256;
    #pragma unroll
    for (int kk = 0; kk < 8; ++kk) {
      bf16x8 b0 = *(const bf16x8*)wpA; wpA += 32;
      bf16x8 b1 = *(const bf16x8*)wpB; wpB += 32;
      #pragma unroll
      for (int m = 0; m < 4; ++m) {
        int t = m*16 + l15;
        bf16x8 af = *(const bf16x8*)&Xs[t*256 + (((kk*4+quad)^(t&7))<<3)];
        pacc[m][0] = MFMA(af, b0, pacc[m][0]);
        pacc[m][1] = MFMA(af, b1, pacc[m][1]);
      }
    }
    float* ob = out + obase;
    #pragma unroll
    for (int n = 0; n < 2; ++n) {
      int dout = wv*32 + n*16 + l15;
      float bv = pb[dout];
      #pragma unroll
      for (int m = 0; m < 4; ++m)
        #pragma unroll
        for (int e = 0; e < 4; ++e) {
          int t = m*16 + quad*4 + e;
          int pix = (wh*8 + (t>>3))*256 + ww*8 + (t&7);
          ob[(size_t)pix*256 + dout] = pacc[m][n][e] + bv;
        }
    }
  }
}

extern "C" void kernel_launch(void* const* d_in, const int* in_sizes, int n_in,
                              void* d_out, int out_size, void* d_ws, size_t ws_size,
                              hipStream_t stream) {
  const float* x  = (const float*)d_in[0];
  const float* qw = (const float*)d_in[1];
  const float* pw = (const float*)d_in[2];
  const float* pb = (const float*)d_in[3];
  const float* bs = (const float*)d_in[4];
  u16* wbf = (u16*)d_ws;                 // 294912 u16 = 576 KB of ws

  cvt_w<<<576, 512, 0, stream>>>(qw, pw, bs, wbf);
  swin<<<4096, 512, 0, stream>>>(x, wbf, wbf + 196608, pb, wbf + 262144, (float*)d_out);
}